// Round 8
// baseline (2708.880 us; speedup 1.0000x reference)
//
#include <hip/hip_runtime.h>
#include <math.h>

#define BATCH   64
#define SEQLEN  128
#define EMBED   512
#define HID     1024
#define NSTEP   127
#define OUT0    65
#define NOUT    62
#define NBLK    512
#define NTHR    512

// LDS layout (floats):
//   wlds [uu 2][k 1536][gate 4] = 12288 @ 0        (48 KB, persistent)
//   red  phaseA 2048 @ 12288, phaseB 1024 @ 14336, phaseC 512 @ 15360
//   c    128 @ 15872
#define REDA_OFF 12288
#define REDB_OFF 14336
#define REDC_OFF 15360
#define C_OFF    15872
#define LDS_FLOATS 16000   // 64000 B

__device__ __forceinline__ float sigmoidf_(float x) { return 1.f / (1.f + expf(-x)); }

// Transpose h0/c0 ([b][u]) into [u][b] working layout.
__global__ __launch_bounds__(256) void init_state(
    const float* __restrict__ h0, const float* __restrict__ c0,
    float* __restrict__ hT, float* __restrict__ cT)
{
    int id = blockIdx.x * 256 + threadIdx.x;   // u*64+b
    int u = id >> 6, b = id & 63;
    hT[id] = h0[b * HID + u];
    cT[id] = c0[b * HID + u];
}

// Build xT[t][k][b] = embed[prob[b][t]][k] (one-time gather+transpose).
__global__ __launch_bounds__(256) void embed_transpose(
    const int* __restrict__ prob, const float* __restrict__ embed,
    float* __restrict__ xT)
{
    __shared__ float xe[64 * 132];
    int t = blockIdx.x;
    int tid = threadIdx.x;
    for (int kt = 0; kt < 4; ++kt) {
        #pragma unroll
        for (int i = 0; i < 8; ++i) {
            int id = tid + i * 256;
            int b  = id >> 5;
            int k4 = id & 31;
            int tok = prob[b * SEQLEN + t];
            float4 v = *(const float4*)(embed + (size_t)tok * EMBED + kt * 128 + k4 * 4);
            *(float4*)(&xe[b * 132 + k4 * 4]) = v;
        }
        __syncthreads();
        #pragma unroll
        for (int i = 0; i < 8; ++i) {
            int id = tid + i * 256;
            int kl = id >> 4;
            int b4 = id & 15;
            float4 v;
            v.x = xe[(b4 * 4 + 0) * 132 + kl];
            v.y = xe[(b4 * 4 + 1) * 132 + kl];
            v.z = xe[(b4 * 4 + 2) * 132 + kl];
            v.w = xe[(b4 * 4 + 3) * 132 + kl];
            *(float4*)(&xT[((size_t)t * EMBED + kt * 128 + kl) * 64 + b4 * 4]) = v;
        }
        __syncthreads();
    }
}

// ===================== persistent path, h-history variant =====================
// Round-8 change: h written to a FRESH buffer per step (h_hist[t]) -> no
// address reuse across steps -> consumer h loads are plain CACHED loads
// (L2 absorbs the 64-block per-XCD broadcast; L3 sees 256 KB/XCD/step).
// Producers keep relaxed agent-scope write-through stores. Workgroup acquire
// fence after the go-spin prevents compiler hoisting of h loads (no cache inv).
__global__ __launch_bounds__(NTHR, 4) void lstm_persist_hist(
    const float* __restrict__ xT, float* __restrict__ h_hist,
    const float* __restrict__ cT,
    const float* __restrict__ w_ih, const float* __restrict__ w_hh,
    const float* __restrict__ b_ih, const float* __restrict__ b_hh,
    const float* __restrict__ w_ans, float* __restrict__ pout,
    int* __restrict__ bar)
{
    __shared__ float lds[LDS_FLOATS];
    const int tid = threadIdx.x;
    const int bid = blockIdx.x;
    const int b   = tid & 63;
    const int ksl = __builtin_amdgcn_readfirstlane(tid >> 6);  // 0..7
    const int u0  = bid * 2;

    int* cnt  = bar + (bid & 7) * 32;   // 8 stripes, 128 B apart
    int* scnt = bar + 256;
    int* go   = bar + 288;

    // one-time: weights -> LDS  [uu][k][gate]
    for (int idx = tid; idx < 12288; idx += NTHR) {
        int r  = idx / 1536;
        int k  = idx - r * 1536;
        int uu = r & 1, gate = r >> 1;
        int row = gate * HID + u0 + uu;
        float v = (k < EMBED) ? w_ih[(size_t)row * EMBED + k]
                              : w_hh[(size_t)row * HID + (k - EMBED)];
        lds[(uu * 1536 + k) * 4 + gate] = v;
    }
    if (tid < 128) lds[C_OFF + tid] = cT[u0 * 64 + tid];

    float bias[2][4], wans[2];
    #pragma unroll
    for (int uu = 0; uu < 2; ++uu) {
        #pragma unroll
        for (int j = 0; j < 4; ++j) {
            int rj = j * HID + u0 + uu;
            bias[uu][j] = b_ih[rj] + b_hh[rj];
        }
        wans[uu] = w_ans[u0 + uu];
    }
    __syncthreads();

    for (int t = 0; t < NSTEP; ++t) {
        const float* xt = xT + (size_t)t * EMBED * 64;
        const float* ht = h_hist + (size_t)t * HID * 64;        // step-t input
        float* hn_buf   = h_hist + (size_t)(t + 1) * HID * 64;  // fresh output buf

        float acc[2][4];
        #pragma unroll
        for (int uu = 0; uu < 2; ++uu)
            #pragma unroll
            for (int j = 0; j < 4; ++j) acc[uu][j] = 0.f;

        // ---- x phase (L2-cached, overlaps barrier tail of step t-1) ----
        const int kx0 = ksl * 64;
        #pragma unroll 4
        for (int g = 0; g < 16; ++g) {
            const int k = kx0 + g * 4;
            float xv[4];
            #pragma unroll
            for (int i = 0; i < 4; ++i) xv[i] = xt[(size_t)(k + i) * 64 + b];
            #pragma unroll
            for (int i = 0; i < 4; ++i) {
                float4 wa = *(const float4*)&lds[(0 * 1536 + k + i) * 4];
                float4 wb = *(const float4*)&lds[(1 * 1536 + k + i) * 4];
                acc[0][0] = fmaf(wa.x, xv[i], acc[0][0]);
                acc[0][1] = fmaf(wa.y, xv[i], acc[0][1]);
                acc[0][2] = fmaf(wa.z, xv[i], acc[0][2]);
                acc[0][3] = fmaf(wa.w, xv[i], acc[0][3]);
                acc[1][0] = fmaf(wb.x, xv[i], acc[1][0]);
                acc[1][1] = fmaf(wb.y, xv[i], acc[1][1]);
                acc[1][2] = fmaf(wb.z, xv[i], acc[1][2]);
                acc[1][3] = fmaf(wb.w, xv[i], acc[1][3]);
            }
        }

        // ---- wait for h(t-1): read-only spin on go ----
        if (t > 0) {
            if (tid == 0) {
                while (__hip_atomic_load(go, __ATOMIC_RELAXED,
                                         __HIP_MEMORY_SCOPE_AGENT) < t)
                    __builtin_amdgcn_s_sleep(1);
            }
            __syncthreads();
            // compiler barrier only (waitcnt, no cache inv at workgroup scope):
            __builtin_amdgcn_fence(__ATOMIC_ACQUIRE, "workgroup");
        }

        // ---- h phase: plain cached loads (fresh addresses every step) ----
        const int kh0 = ksl * 128;
        #pragma unroll 4
        for (int g = 0; g < 32; ++g) {
            const int kh = kh0 + g * 4;
            float hv[4];
            #pragma unroll
            for (int i = 0; i < 4; ++i)
                hv[i] = ht[(size_t)(kh + i) * 64 + b];
            #pragma unroll
            for (int i = 0; i < 4; ++i) {
                const int kw = EMBED + kh + i;
                float4 wa = *(const float4*)&lds[(0 * 1536 + kw) * 4];
                float4 wb = *(const float4*)&lds[(1 * 1536 + kw) * 4];
                acc[0][0] = fmaf(wa.x, hv[i], acc[0][0]);
                acc[0][1] = fmaf(wa.y, hv[i], acc[0][1]);
                acc[0][2] = fmaf(wa.z, hv[i], acc[0][2]);
                acc[0][3] = fmaf(wa.w, hv[i], acc[0][3]);
                acc[1][0] = fmaf(wb.x, hv[i], acc[1][0]);
                acc[1][1] = fmaf(wb.y, hv[i], acc[1][1]);
                acc[1][2] = fmaf(wb.z, hv[i], acc[1][2]);
                acc[1][3] = fmaf(wb.w, hv[i], acc[1][3]);
            }
        }

        // ---- tree reduction 8 -> 4 -> 2 -> 1 waves ----
        if (ksl >= 4) {
            #pragma unroll
            for (int uu = 0; uu < 2; ++uu)
                #pragma unroll
                for (int j = 0; j < 4; ++j)
                    lds[REDA_OFF + (((ksl - 4) * 8) + uu * 4 + j) * 64 + b] = acc[uu][j];
        }
        __syncthreads();
        if (ksl < 4) {
            #pragma unroll
            for (int uu = 0; uu < 2; ++uu)
                #pragma unroll
                for (int j = 0; j < 4; ++j)
                    acc[uu][j] += lds[REDA_OFF + ((ksl * 8) + uu * 4 + j) * 64 + b];
        }
        if (ksl == 2 || ksl == 3) {
            #pragma unroll
            for (int uu = 0; uu < 2; ++uu)
                #pragma unroll
                for (int j = 0; j < 4; ++j)
                    lds[REDB_OFF + (((ksl - 2) * 8) + uu * 4 + j) * 64 + b] = acc[uu][j];
        }
        __syncthreads();
        if (ksl < 2) {
            #pragma unroll
            for (int uu = 0; uu < 2; ++uu)
                #pragma unroll
                for (int j = 0; j < 4; ++j)
                    acc[uu][j] += lds[REDB_OFF + ((ksl * 8) + uu * 4 + j) * 64 + b];
        }
        if (ksl == 1) {
            #pragma unroll
            for (int uu = 0; uu < 2; ++uu)
                #pragma unroll
                for (int j = 0; j < 4; ++j)
                    lds[REDC_OFF + (uu * 4 + j) * 64 + b] = acc[uu][j];
        }
        __syncthreads();
        if (ksl == 0) {
            float hvals[2];
            #pragma unroll
            for (int uu = 0; uu < 2; ++uu) {
                #pragma unroll
                for (int j = 0; j < 4; ++j)
                    acc[uu][j] += lds[REDC_OFF + (uu * 4 + j) * 64 + b];
                float i_g = sigmoidf_(acc[uu][0] + bias[uu][0]);
                float f_g = sigmoidf_(acc[uu][1] + bias[uu][1]);
                float g_g = tanhf   (acc[uu][2] + bias[uu][2]);
                float o_g = sigmoidf_(acc[uu][3] + bias[uu][3]);
                float c_old = lds[C_OFF + uu * 64 + b];
                float c_new = f_g * c_old + i_g * g_g;
                float h_new = o_g * tanhf(c_new);
                lds[C_OFF + uu * 64 + b] = c_new;
                __hip_atomic_store(&hn_buf[(u0 + uu) * 64 + b], h_new,
                                   __ATOMIC_RELAXED, __HIP_MEMORY_SCOPE_AGENT);
                hvals[uu] = h_new;
            }
            if (t >= OUT0) {
                pout[((size_t)(t - OUT0) * NBLK + bid) * 64 + b] =
                    hvals[0] * wans[0] + hvals[1] * wans[1];
            }
        }

        if (t == NSTEP - 1) break;

        // ---- arrive: striped counters -> super -> go ----
        __syncthreads();
        if (tid == 0) {
            int r = __hip_atomic_fetch_add(cnt, 1, __ATOMIC_RELAXED,
                                           __HIP_MEMORY_SCOPE_AGENT);
            if (r == 64 * (t + 1) - 1) {
                int s2 = __hip_atomic_fetch_add(scnt, 1, __ATOMIC_RELAXED,
                                                __HIP_MEMORY_SCOPE_AGENT);
                if (s2 == 8 * (t + 1) - 1)
                    __hip_atomic_store(go, t + 1, __ATOMIC_RELAXED,
                                       __HIP_MEMORY_SCOPE_AGENT);
            }
        }
    }
}

// ===================== persistent path, round-7 variant (ws-small fallback) ==
__global__ __launch_bounds__(NTHR, 4) void lstm_persist(
    const float* __restrict__ xT, float* __restrict__ hb0, float* __restrict__ hb1,
    const float* __restrict__ cT,
    const float* __restrict__ w_ih, const float* __restrict__ w_hh,
    const float* __restrict__ b_ih, const float* __restrict__ b_hh,
    const float* __restrict__ w_ans, float* __restrict__ pout,
    int* __restrict__ bar)
{
    __shared__ float lds[LDS_FLOATS];
    const int tid = threadIdx.x;
    const int bid = blockIdx.x;
    const int b   = tid & 63;
    const int ksl = __builtin_amdgcn_readfirstlane(tid >> 6);
    const int u0  = bid * 2;

    int* cnt  = bar + (bid & 7) * 32;
    int* scnt = bar + 256;
    int* go   = bar + 288;

    for (int idx = tid; idx < 12288; idx += NTHR) {
        int r  = idx / 1536;
        int k  = idx - r * 1536;
        int uu = r & 1, gate = r >> 1;
        int row = gate * HID + u0 + uu;
        float v = (k < EMBED) ? w_ih[(size_t)row * EMBED + k]
                              : w_hh[(size_t)row * HID + (k - EMBED)];
        lds[(uu * 1536 + k) * 4 + gate] = v;
    }
    if (tid < 128) lds[C_OFF + tid] = cT[u0 * 64 + tid];

    float bias[2][4], wans[2];
    #pragma unroll
    for (int uu = 0; uu < 2; ++uu) {
        #pragma unroll
        for (int j = 0; j < 4; ++j) {
            int rj = j * HID + u0 + uu;
            bias[uu][j] = b_ih[rj] + b_hh[rj];
        }
        wans[uu] = w_ans[u0 + uu];
    }
    __syncthreads();

    for (int t = 0; t < NSTEP; ++t) {
        const float* xt = xT + (size_t)t * EMBED * 64;
        const float* ht = (t & 1) ? hb1 : hb0;
        float* hn_buf   = (t & 1) ? hb0 : hb1;

        float acc[2][4];
        #pragma unroll
        for (int uu = 0; uu < 2; ++uu)
            #pragma unroll
            for (int j = 0; j < 4; ++j) acc[uu][j] = 0.f;

        const int kx0 = ksl * 64;
        #pragma unroll 4
        for (int g = 0; g < 16; ++g) {
            const int k = kx0 + g * 4;
            float xv[4];
            #pragma unroll
            for (int i = 0; i < 4; ++i) xv[i] = xt[(size_t)(k + i) * 64 + b];
            #pragma unroll
            for (int i = 0; i < 4; ++i) {
                float4 wa = *(const float4*)&lds[(0 * 1536 + k + i) * 4];
                float4 wb = *(const float4*)&lds[(1 * 1536 + k + i) * 4];
                acc[0][0] = fmaf(wa.x, xv[i], acc[0][0]);
                acc[0][1] = fmaf(wa.y, xv[i], acc[0][1]);
                acc[0][2] = fmaf(wa.z, xv[i], acc[0][2]);
                acc[0][3] = fmaf(wa.w, xv[i], acc[0][3]);
                acc[1][0] = fmaf(wb.x, xv[i], acc[1][0]);
                acc[1][1] = fmaf(wb.y, xv[i], acc[1][1]);
                acc[1][2] = fmaf(wb.z, xv[i], acc[1][2]);
                acc[1][3] = fmaf(wb.w, xv[i], acc[1][3]);
            }
        }

        if (t > 0) {
            if (tid == 0) {
                while (__hip_atomic_load(go, __ATOMIC_RELAXED,
                                         __HIP_MEMORY_SCOPE_AGENT) < t)
                    __builtin_amdgcn_s_sleep(1);
            }
            __syncthreads();
        }

        const int kh0 = ksl * 128;
        #pragma unroll 4
        for (int g = 0; g < 32; ++g) {
            const int kh = kh0 + g * 4;
            float hv[4];
            #pragma unroll
            for (int i = 0; i < 4; ++i)
                hv[i] = __hip_atomic_load(&ht[(size_t)(kh + i) * 64 + b],
                                          __ATOMIC_RELAXED, __HIP_MEMORY_SCOPE_AGENT);
            #pragma unroll
            for (int i = 0; i < 4; ++i) {
                const int kw = EMBED + kh + i;
                float4 wa = *(const float4*)&lds[(0 * 1536 + kw) * 4];
                float4 wb = *(const float4*)&lds[(1 * 1536 + kw) * 4];
                acc[0][0] = fmaf(wa.x, hv[i], acc[0][0]);
                acc[0][1] = fmaf(wa.y, hv[i], acc[0][1]);
                acc[0][2] = fmaf(wa.z, hv[i], acc[0][2]);
                acc[0][3] = fmaf(wa.w, hv[i], acc[0][3]);
                acc[1][0] = fmaf(wb.x, hv[i], acc[1][0]);
                acc[1][1] = fmaf(wb.y, hv[i], acc[1][1]);
                acc[1][2] = fmaf(wb.z, hv[i], acc[1][2]);
                acc[1][3] = fmaf(wb.w, hv[i], acc[1][3]);
            }
        }

        if (ksl >= 4) {
            #pragma unroll
            for (int uu = 0; uu < 2; ++uu)
                #pragma unroll
                for (int j = 0; j < 4; ++j)
                    lds[REDA_OFF + (((ksl - 4) * 8) + uu * 4 + j) * 64 + b] = acc[uu][j];
        }
        __syncthreads();
        if (ksl < 4) {
            #pragma unroll
            for (int uu = 0; uu < 2; ++uu)
                #pragma unroll
                for (int j = 0; j < 4; ++j)
                    acc[uu][j] += lds[REDA_OFF + ((ksl * 8) + uu * 4 + j) * 64 + b];
        }
        if (ksl == 2 || ksl == 3) {
            #pragma unroll
            for (int uu = 0; uu < 2; ++uu)
                #pragma unroll
                for (int j = 0; j < 4; ++j)
                    lds[REDB_OFF + (((ksl - 2) * 8) + uu * 4 + j) * 64 + b] = acc[uu][j];
        }
        __syncthreads();
        if (ksl < 2) {
            #pragma unroll
            for (int uu = 0; uu < 2; ++uu)
                #pragma unroll
                for (int j = 0; j < 4; ++j)
                    acc[uu][j] += lds[REDB_OFF + ((ksl * 8) + uu * 4 + j) * 64 + b];
        }
        if (ksl == 1) {
            #pragma unroll
            for (int uu = 0; uu < 2; ++uu)
                #pragma unroll
                for (int j = 0; j < 4; ++j)
                    lds[REDC_OFF + (uu * 4 + j) * 64 + b] = acc[uu][j];
        }
        __syncthreads();
        if (ksl == 0) {
            float hvals[2];
            #pragma unroll
            for (int uu = 0; uu < 2; ++uu) {
                #pragma unroll
                for (int j = 0; j < 4; ++j)
                    acc[uu][j] += lds[REDC_OFF + (uu * 4 + j) * 64 + b];
                float i_g = sigmoidf_(acc[uu][0] + bias[uu][0]);
                float f_g = sigmoidf_(acc[uu][1] + bias[uu][1]);
                float g_g = tanhf   (acc[uu][2] + bias[uu][2]);
                float o_g = sigmoidf_(acc[uu][3] + bias[uu][3]);
                float c_old = lds[C_OFF + uu * 64 + b];
                float c_new = f_g * c_old + i_g * g_g;
                float h_new = o_g * tanhf(c_new);
                lds[C_OFF + uu * 64 + b] = c_new;
                __hip_atomic_store(&hn_buf[(u0 + uu) * 64 + b], h_new,
                                   __ATOMIC_RELAXED, __HIP_MEMORY_SCOPE_AGENT);
                hvals[uu] = h_new;
            }
            if (t >= OUT0) {
                pout[((size_t)(t - OUT0) * NBLK + bid) * 64 + b] =
                    hvals[0] * wans[0] + hvals[1] * wans[1];
            }
        }

        if (t == NSTEP - 1) break;

        __syncthreads();
        if (tid == 0) {
            int r = __hip_atomic_fetch_add(cnt, 1, __ATOMIC_RELAXED,
                                           __HIP_MEMORY_SCOPE_AGENT);
            if (r == 64 * (t + 1) - 1) {
                int s2 = __hip_atomic_fetch_add(scnt, 1, __ATOMIC_RELAXED,
                                                __HIP_MEMORY_SCOPE_AGENT);
                if (s2 == 8 * (t + 1) - 1)
                    __hip_atomic_store(go, t + 1, __ATOMIC_RELAXED,
                                       __HIP_MEMORY_SCOPE_AGENT);
            }
        }
    }
}

// out[b][col] = sum over 512 block partials + bias.  (persist layout)
__global__ __launch_bounds__(256) void finalize_persist(
    const float* __restrict__ pout, const float* __restrict__ b_ans,
    float* __restrict__ out)
{
    __shared__ float r[256];
    int col = blockIdx.x;
    int tid = threadIdx.x;
    int b = tid & 63, q = tid >> 6;
    float s = 0.f;
    for (int i = q; i < NBLK; i += 4)
        s += pout[((size_t)col * NBLK + i) * 64 + b];
    r[tid] = s;
    __syncthreads();
    if (tid < 64)
        out[tid * NOUT + col] = r[tid] + r[64 + tid] + r[128 + tid] + r[192 + tid]
                              + b_ans[0];
}

// ===================== per-step fallback (round-3 proven) =====================
#define F_HEADOFF 4096
__global__ __launch_bounds__(1024, 4) void lstm_step_fb(
    const float* __restrict__ xT, const float* __restrict__ hT_in,
    float* __restrict__ hT_out, float* __restrict__ cT,
    const float* __restrict__ w_ih, const float* __restrict__ w_hh,
    const float* __restrict__ b_ih, const float* __restrict__ b_hh,
    const float* __restrict__ w_ans, float* __restrict__ pout, int t)
{
    __shared__ float lds[F_HEADOFF + 256];
    const int tid = threadIdx.x;
    const int bid = blockIdx.x;
    const int b   = tid & 63;
    const int ws  = __builtin_amdgcn_readfirstlane(tid >> 6);
    const int uu  = ws & 3;
    const int ksl = ws >> 2;
    const int u   = bid * 4 + uu;

    const float* wr_i[4];
    const float* wr_h[4];
    #pragma unroll
    for (int j = 0; j < 4; ++j) {
        wr_i[j] = w_ih + (size_t)(j * HID + u) * EMBED;
        wr_h[j] = w_hh + (size_t)(j * HID + u) * HID;
    }
    float acc[4];
    acc[0] = acc[1] = acc[2] = acc[3] = 0.f;
    {
        const float* xt = xT + (size_t)t * EMBED * 64;
        const int k0 = ksl * 128;
        #pragma unroll 4
        for (int g = 0; g < 32; ++g) {
            const int k = k0 + g * 4;
            float4 wv0 = *(const float4*)(wr_i[0] + k);
            float4 wv1 = *(const float4*)(wr_i[1] + k);
            float4 wv2 = *(const float4*)(wr_i[2] + k);
            float4 wv3 = *(const float4*)(wr_i[3] + k);
            float x0 = xt[(k + 0) * 64 + b];
            float x1 = xt[(k + 1) * 64 + b];
            float x2 = xt[(k + 2) * 64 + b];
            float x3 = xt[(k + 3) * 64 + b];
            acc[0] = fmaf(wv0.x, x0, acc[0]); acc[0] = fmaf(wv0.y, x1, acc[0]);
            acc[0] = fmaf(wv0.z, x2, acc[0]); acc[0] = fmaf(wv0.w, x3, acc[0]);
            acc[1] = fmaf(wv1.x, x0, acc[1]); acc[1] = fmaf(wv1.y, x1, acc[1]);
            acc[1] = fmaf(wv1.z, x2, acc[1]); acc[1] = fmaf(wv1.w, x3, acc[1]);
            acc[2] = fmaf(wv2.x, x0, acc[2]); acc[2] = fmaf(wv2.y, x1, acc[2]);
            acc[2] = fmaf(wv2.z, x2, acc[2]); acc[2] = fmaf(wv2.w, x3, acc[2]);
            acc[3] = fmaf(wv3.x, x0, acc[3]); acc[3] = fmaf(wv3.y, x1, acc[3]);
            acc[3] = fmaf(wv3.z, x2, acc[3]); acc[3] = fmaf(wv3.w, x3, acc[3]);
        }
    }
    {
        const int k0 = ksl * 256;
        #pragma unroll 4
        for (int g = 0; g < 64; ++g) {
            const int k = k0 + g * 4;
            float4 wv0 = *(const float4*)(wr_h[0] + k);
            float4 wv1 = *(const float4*)(wr_h[1] + k);
            float4 wv2 = *(const float4*)(wr_h[2] + k);
            float4 wv3 = *(const float4*)(wr_h[3] + k);
            float x0 = hT_in[(k + 0) * 64 + b];
            float x1 = hT_in[(k + 1) * 64 + b];
            float x2 = hT_in[(k + 2) * 64 + b];
            float x3 = hT_in[(k + 3) * 64 + b];
            acc[0] = fmaf(wv0.x, x0, acc[0]); acc[0] = fmaf(wv0.y, x1, acc[0]);
            acc[0] = fmaf(wv0.z, x2, acc[0]); acc[0] = fmaf(wv0.w, x3, acc[0]);
            acc[1] = fmaf(wv1.x, x0, acc[1]); acc[1] = fmaf(wv1.y, x1, acc[1]);
            acc[1] = fmaf(wv1.z, x2, acc[1]); acc[1] = fmaf(wv1.w, x3, acc[1]);
            acc[2] = fmaf(wv2.x, x0, acc[2]); acc[2] = fmaf(wv2.y, x1, acc[2]);
            acc[2] = fmaf(wv2.z, x2, acc[2]); acc[2] = fmaf(wv2.w, x3, acc[2]);
            acc[3] = fmaf(wv3.x, x0, acc[3]); acc[3] = fmaf(wv3.y, x1, acc[3]);
            acc[3] = fmaf(wv3.z, x2, acc[3]); acc[3] = fmaf(wv3.w, x3, acc[3]);
        }
    }
    #pragma unroll
    for (int j = 0; j < 4; ++j)
        lds[((ksl * 4 + uu) * 4 + j) * 64 + b] = acc[j];
    __syncthreads();
    if (tid < 256) {
        int b2  = tid & 63;
        int uu2 = tid >> 6;
        int u2  = bid * 4 + uu2;
        float s[4];
        #pragma unroll
        for (int j = 0; j < 4; ++j) {
            s[j] = lds[((0 * 4 + uu2) * 4 + j) * 64 + b2]
                 + lds[((1 * 4 + uu2) * 4 + j) * 64 + b2]
                 + lds[((2 * 4 + uu2) * 4 + j) * 64 + b2]
                 + lds[((3 * 4 + uu2) * 4 + j) * 64 + b2];
            int rj = j * HID + u2;
            s[j] += b_ih[rj] + b_hh[rj];
        }
        float ig = sigmoidf_(s[0]);
        float fg = sigmoidf_(s[1]);
        float gg = tanhf(s[2]);
        float og = sigmoidf_(s[3]);
        float cn = fg * cT[u2 * 64 + b2] + ig * gg;
        float hn = og * tanhf(cn);
        cT[u2 * 64 + b2]     = cn;
        hT_out[u2 * 64 + b2] = hn;
        lds[F_HEADOFF + uu2 * 64 + b2] = hn * w_ans[u2];
    }
    __syncthreads();
    if (t >= OUT0 && tid < 64) {
        float sum = lds[F_HEADOFF + tid]       + lds[F_HEADOFF + 64 + tid]
                  + lds[F_HEADOFF + 128 + tid] + lds[F_HEADOFF + 192 + tid];
        pout[((size_t)((t - OUT0) * 64 + tid)) * 256 + bid] = sum;
    }
}

__global__ __launch_bounds__(64) void finalize_fb(
    const float* __restrict__ pout, const float* __restrict__ b_ans,
    float* __restrict__ out)
{
    int blk  = blockIdx.x;
    int col  = blk >> 6;
    int bb   = blk & 63;
    int lane = threadIdx.x;
    const float* p = pout + (size_t)(col * 64 + bb) * 256;
    float s = p[lane] + p[lane + 64] + p[lane + 128] + p[lane + 192];
    #pragma unroll
    for (int off = 32; off > 0; off >>= 1) s += __shfl_down(s, off);
    if (lane == 0) out[bb * NOUT + col] = s + b_ans[0];
}

extern "C" void kernel_launch(void* const* d_in, const int* in_sizes, int n_in,
                              void* d_out, int out_size, void* d_ws, size_t ws_size,
                              hipStream_t stream)
{
    const int*   prob  = (const int*)  d_in[0];
    const float* embed = (const float*)d_in[2];
    const float* w_ih  = (const float*)d_in[3];
    const float* w_hh  = (const float*)d_in[4];
    const float* b_ih  = (const float*)d_in[5];
    const float* b_hh  = (const float*)d_in[6];
    const float* w_ans = (const float*)d_in[7];
    const float* b_ans = (const float*)d_in[8];
    const float* h0    = (const float*)d_in[9];
    const float* c0    = (const float*)d_in[10];

    float* ws = (float*)d_ws;

    // h-hist layout (needs ~58.6 MB)
    const size_t HIST_NEED_BYTES = ((size_t)14647808 + 512) * 4;

    if (ws_size >= HIST_NEED_BYTES) {
        float* cT     = ws;                    // 65,536
        float* pout   = ws + 65536;            // 2,031,616
        float* xT     = ws + 2097152;          // 4,161,536
        float* h_hist = ws + 6258688;          // 128*65,536 = 8,388,608
        int*   bar    = (int*)(ws + 14647296); // 512 ints

        hipMemsetAsync(bar, 0, 2048, stream);
        init_state<<<256, 256, 0, stream>>>(h0, c0, h_hist, cT);
        embed_transpose<<<NSTEP, 256, 0, stream>>>(prob, embed, xT);

        void* args[] = {
            (void*)&xT, (void*)&h_hist, (void*)&cT,
            (void*)&w_ih, (void*)&w_hh, (void*)&b_ih, (void*)&b_hh,
            (void*)&w_ans, (void*)&pout, (void*)&bar
        };
        hipError_t err = hipLaunchCooperativeKernel((const void*)lstm_persist_hist,
                                                    dim3(NBLK), dim3(NTHR),
                                                    args, 0, stream);
        if (err == hipSuccess) {
            finalize_persist<<<NOUT, 256, 0, stream>>>(pout, b_ans, (float*)d_out);
        } else {
            for (int t = 0; t < NSTEP; ++t) {
                float* hin  = h_hist + (size_t)(t & 1) * 65536;
                float* hout = h_hist + (size_t)((t + 1) & 1) * 65536;
                lstm_step_fb<<<256, 1024, 0, stream>>>(xT, hin, hout, cT, w_ih, w_hh,
                                                       b_ih, b_hh, w_ans, pout, t);
            }
            finalize_fb<<<NOUT * 64, 64, 0, stream>>>(pout, b_ans, (float*)d_out);
        }
    } else {
        // round-7 layout
        float* hT0  = ws;
        float* hT1  = ws + 65536;
        float* cT   = ws + 131072;
        float* pout = ws + 196608;
        float* xT   = ws + 2228224;
        int*   bar  = (int*)(ws + 6389760);

        hipMemsetAsync(bar, 0, 2048, stream);
        init_state<<<256, 256, 0, stream>>>(h0, c0, hT0, cT);
        embed_transpose<<<NSTEP, 256, 0, stream>>>(prob, embed, xT);

        void* args[] = {
            (void*)&xT, (void*)&hT0, (void*)&hT1, (void*)&cT,
            (void*)&w_ih, (void*)&w_hh, (void*)&b_ih, (void*)&b_hh,
            (void*)&w_ans, (void*)&pout, (void*)&bar
        };
        hipError_t err = hipLaunchCooperativeKernel((const void*)lstm_persist,
                                                    dim3(NBLK), dim3(NTHR),
                                                    args, 0, stream);
        if (err == hipSuccess) {
            finalize_persist<<<NOUT, 256, 0, stream>>>(pout, b_ans, (float*)d_out);
        } else {
            for (int t = 0; t < NSTEP; ++t) {
                float* hin  = (t & 1) ? hT1 : hT0;
                float* hout = (t & 1) ? hT0 : hT1;
                lstm_step_fb<<<256, 1024, 0, stream>>>(xT, hin, hout, cT, w_ih, w_hh,
                                                       b_ih, b_hh, w_ans, pout, t);
            }
            finalize_fb<<<NOUT * 64, 64, 0, stream>>>(pout, b_ans, (float*)d_out);
        }
    }
}

// Round 9
// 2545.188 us; speedup vs baseline: 1.0643x; 1.0643x over previous
//
#include <hip/hip_runtime.h>
#include <math.h>

#define BATCH   64
#define SEQLEN  128
#define EMBED   512
#define HID     1024
#define NSTEP   127
#define OUT0    65
#define NOUT    62
#define NBLK    512
#define NTHR    512

// LDS layout (floats):
//   wlds [uu 2][k 1536][gate 4] = 12288 @ 0        (48 KB, persistent)
//   red  phaseA 2048 @ 12288, phaseB 1024 @ 14336, phaseC 512 @ 15360
//   c    128 @ 15872   (c-state: [uu][b])
//   head 128 @ 16000   (h*w_ans handoff: [uu][b])
#define REDA_OFF 12288
#define REDB_OFF 14336
#define REDC_OFF 15360
#define C_OFF    15872
#define HEAD_OFF 16000
#define LDS_FLOATS 16128   // 64512 B; 2 blocks/CU = 129 KB < 160 KB

__device__ __forceinline__ float sigmoidf_(float x) { return 1.f / (1.f + expf(-x)); }

// Transpose h0/c0 ([b][u]) into [u][b] working layout.
__global__ __launch_bounds__(256) void init_state(
    const float* __restrict__ h0, const float* __restrict__ c0,
    float* __restrict__ hT, float* __restrict__ cT)
{
    int id = blockIdx.x * 256 + threadIdx.x;   // u*64+b
    int u = id >> 6, b = id & 63;
    hT[id] = h0[b * HID + u];
    cT[id] = c0[b * HID + u];
}

// Build xT[t][k][b] = embed[prob[b][t]][k] (one-time gather+transpose).
__global__ __launch_bounds__(256) void embed_transpose(
    const int* __restrict__ prob, const float* __restrict__ embed,
    float* __restrict__ xT)
{
    __shared__ float xe[64 * 132];
    int t = blockIdx.x;
    int tid = threadIdx.x;
    for (int kt = 0; kt < 4; ++kt) {
        #pragma unroll
        for (int i = 0; i < 8; ++i) {
            int id = tid + i * 256;
            int b  = id >> 5;
            int k4 = id & 31;
            int tok = prob[b * SEQLEN + t];
            float4 v = *(const float4*)(embed + (size_t)tok * EMBED + kt * 128 + k4 * 4);
            *(float4*)(&xe[b * 132 + k4 * 4]) = v;
        }
        __syncthreads();
        #pragma unroll
        for (int i = 0; i < 8; ++i) {
            int id = tid + i * 256;
            int kl = id >> 4;
            int b4 = id & 15;
            float4 v;
            v.x = xe[(b4 * 4 + 0) * 132 + kl];
            v.y = xe[(b4 * 4 + 1) * 132 + kl];
            v.z = xe[(b4 * 4 + 2) * 132 + kl];
            v.w = xe[(b4 * 4 + 3) * 132 + kl];
            *(float4*)(&xT[((size_t)t * EMBED + kt * 128 + kl) * 64 + b4 * 4]) = v;
        }
        __syncthreads();
    }
}

// ===================== persistent path, per-slice dataflow =====================
// Round-9 change: no global barrier. Producer blocks of unit-slice s
// (bid in [s*64,(s+1)*64)) arrive on sliceCnt[s]; 64th arriver publishes
// sliceGo[s]=t+1. Consumer WAVE ksl spins only on sliceGo[ksl] (its own
// 128-unit h-slice), then runs its h-FMAs -> 8-way pipelined dataflow;
// the slowest producer gates only 1/8 of the work. Gate finalize split
// across waves 0 and 1 (one unit each) to halve the serial tail.
__global__ __launch_bounds__(NTHR, 4) void lstm_persist_hist(
    const float* __restrict__ xT, float* __restrict__ h_hist,
    const float* __restrict__ cT,
    const float* __restrict__ w_ih, const float* __restrict__ w_hh,
    const float* __restrict__ b_ih, const float* __restrict__ b_hh,
    const float* __restrict__ w_ans, float* __restrict__ pout,
    int* __restrict__ bar)
{
    __shared__ float lds[LDS_FLOATS];
    const int tid = threadIdx.x;
    const int bid = blockIdx.x;
    const int b   = tid & 63;
    const int ksl = __builtin_amdgcn_readfirstlane(tid >> 6);  // 0..7
    const int u0  = bid * 2;

    int* sliceCnt = bar + (bid >> 6) * 32;    // producer arrive line (this block's slice)
    int* mySlice  = bar + 256 + (bid >> 6) * 32;   // go flag this block publishes
    int* waitGo   = bar + 256 + ksl * 32;          // go flag this wave consumes

    // one-time: weights -> LDS  [uu][k][gate]
    for (int idx = tid; idx < 12288; idx += NTHR) {
        int r  = idx / 1536;
        int k  = idx - r * 1536;
        int uu = r & 1, gate = r >> 1;
        int row = gate * HID + u0 + uu;
        float v = (k < EMBED) ? w_ih[(size_t)row * EMBED + k]
                              : w_hh[(size_t)row * HID + (k - EMBED)];
        lds[(uu * 1536 + k) * 4 + gate] = v;
    }
    if (tid < 128) lds[C_OFF + tid] = cT[u0 * 64 + tid];

    float bias[2][4], wans[2];
    #pragma unroll
    for (int uu = 0; uu < 2; ++uu) {
        #pragma unroll
        for (int j = 0; j < 4; ++j) {
            int rj = j * HID + u0 + uu;
            bias[uu][j] = b_ih[rj] + b_hh[rj];
        }
        wans[uu] = w_ans[u0 + uu];
    }
    __syncthreads();

    for (int t = 0; t < NSTEP; ++t) {
        const float* xt = xT + (size_t)t * EMBED * 64;
        const float* ht = h_hist + (size_t)t * HID * 64;
        float* hn_buf   = h_hist + (size_t)(t + 1) * HID * 64;

        float acc[2][4];
        #pragma unroll
        for (int uu = 0; uu < 2; ++uu)
            #pragma unroll
            for (int j = 0; j < 4; ++j) acc[uu][j] = 0.f;

        // ---- x phase (independent of h(t-1); overlaps other blocks' tails) ----
        const int kx0 = ksl * 64;
        #pragma unroll 4
        for (int g = 0; g < 16; ++g) {
            const int k = kx0 + g * 4;
            float xv[4];
            #pragma unroll
            for (int i = 0; i < 4; ++i) xv[i] = xt[(size_t)(k + i) * 64 + b];
            #pragma unroll
            for (int i = 0; i < 4; ++i) {
                float4 wa = *(const float4*)&lds[(0 * 1536 + k + i) * 4];
                float4 wb = *(const float4*)&lds[(1 * 1536 + k + i) * 4];
                acc[0][0] = fmaf(wa.x, xv[i], acc[0][0]);
                acc[0][1] = fmaf(wa.y, xv[i], acc[0][1]);
                acc[0][2] = fmaf(wa.z, xv[i], acc[0][2]);
                acc[0][3] = fmaf(wa.w, xv[i], acc[0][3]);
                acc[1][0] = fmaf(wb.x, xv[i], acc[1][0]);
                acc[1][1] = fmaf(wb.y, xv[i], acc[1][1]);
                acc[1][2] = fmaf(wb.z, xv[i], acc[1][2]);
                acc[1][3] = fmaf(wb.w, xv[i], acc[1][3]);
            }
        }

        // ---- per-wave wait: only THIS wave's h-slice must be ready ----
        if (t > 0) {
            // all 64 lanes load the same address -> one request per poll
            while (__hip_atomic_load(waitGo, __ATOMIC_RELAXED,
                                     __HIP_MEMORY_SCOPE_AGENT) < t)
                __builtin_amdgcn_s_sleep(4);
            __builtin_amdgcn_fence(__ATOMIC_ACQUIRE, "workgroup"); // no cache inv
        }

        // ---- h phase: this wave's 128-k slice, plain cached loads ----
        const int kh0 = ksl * 128;
        #pragma unroll 4
        for (int g = 0; g < 32; ++g) {
            const int kh = kh0 + g * 4;
            float hv[4];
            #pragma unroll
            for (int i = 0; i < 4; ++i)
                hv[i] = ht[(size_t)(kh + i) * 64 + b];
            #pragma unroll
            for (int i = 0; i < 4; ++i) {
                const int kw = EMBED + kh + i;
                float4 wa = *(const float4*)&lds[(0 * 1536 + kw) * 4];
                float4 wb = *(const float4*)&lds[(1 * 1536 + kw) * 4];
                acc[0][0] = fmaf(wa.x, hv[i], acc[0][0]);
                acc[0][1] = fmaf(wa.y, hv[i], acc[0][1]);
                acc[0][2] = fmaf(wa.z, hv[i], acc[0][2]);
                acc[0][3] = fmaf(wa.w, hv[i], acc[0][3]);
                acc[1][0] = fmaf(wb.x, hv[i], acc[1][0]);
                acc[1][1] = fmaf(wb.y, hv[i], acc[1][1]);
                acc[1][2] = fmaf(wb.z, hv[i], acc[1][2]);
                acc[1][3] = fmaf(wb.w, hv[i], acc[1][3]);
            }
        }

        // ---- tree reduction 8 -> 4 -> 2, then split finalize ----
        if (ksl >= 4) {
            #pragma unroll
            for (int uu = 0; uu < 2; ++uu)
                #pragma unroll
                for (int j = 0; j < 4; ++j)
                    lds[REDA_OFF + (((ksl - 4) * 8) + uu * 4 + j) * 64 + b] = acc[uu][j];
        }
        __syncthreads();
        if (ksl < 4) {
            #pragma unroll
            for (int uu = 0; uu < 2; ++uu)
                #pragma unroll
                for (int j = 0; j < 4; ++j)
                    acc[uu][j] += lds[REDA_OFF + ((ksl * 8) + uu * 4 + j) * 64 + b];
        }
        if (ksl == 2 || ksl == 3) {
            #pragma unroll
            for (int uu = 0; uu < 2; ++uu)
                #pragma unroll
                for (int j = 0; j < 4; ++j)
                    lds[REDB_OFF + (((ksl - 2) * 8) + uu * 4 + j) * 64 + b] = acc[uu][j];
        }
        __syncthreads();
        if (ksl < 2) {
            #pragma unroll
            for (int uu = 0; uu < 2; ++uu)
                #pragma unroll
                for (int j = 0; j < 4; ++j)
                    acc[uu][j] += lds[REDB_OFF + ((ksl * 8) + uu * 4 + j) * 64 + b];
        }
        // phase C': swap halves so wave0 finalizes unit0, wave1 finalizes unit1
        if (ksl == 0) {
            #pragma unroll
            for (int j = 0; j < 4; ++j)
                lds[REDC_OFF + j * 64 + b] = acc[1][j];          // uu1 half from wave0
        }
        if (ksl == 1) {
            #pragma unroll
            for (int j = 0; j < 4; ++j)
                lds[REDC_OFF + (4 + j) * 64 + b] = acc[0][j];    // uu0 half from wave1
        }
        __syncthreads();
        if (ksl < 2) {
            const int uu = ksl;                                  // wave0->unit0, wave1->unit1
            float s[4];
            if (ksl == 0) {
                #pragma unroll
                for (int j = 0; j < 4; ++j)
                    s[j] = acc[0][j] + lds[REDC_OFF + (4 + j) * 64 + b];
            } else {
                #pragma unroll
                for (int j = 0; j < 4; ++j)
                    s[j] = acc[1][j] + lds[REDC_OFF + j * 64 + b];
            }
            float i_g = sigmoidf_(s[0] + bias[uu][0]);
            float f_g = sigmoidf_(s[1] + bias[uu][1]);
            float g_g = tanhf   (s[2] + bias[uu][2]);
            float o_g = sigmoidf_(s[3] + bias[uu][3]);
            float c_old = lds[C_OFF + uu * 64 + b];
            float c_new = f_g * c_old + i_g * g_g;
            float h_new = o_g * tanhf(c_new);
            lds[C_OFF + uu * 64 + b] = c_new;
            __hip_atomic_store(&hn_buf[(u0 + uu) * 64 + b], h_new,
                               __ATOMIC_RELAXED, __HIP_MEMORY_SCOPE_AGENT);
            lds[HEAD_OFF + uu * 64 + b] = h_new * wans[uu];
        }

        __syncthreads();   // drains waves 0/1 h-stores (vmcnt 0) before arrive
        if (t >= OUT0 && tid < 64) {
            pout[((size_t)(t - OUT0) * NBLK + bid) * 64 + b] =
                lds[HEAD_OFF + b] + lds[HEAD_OFF + 64 + b];
        }
        if (t == NSTEP - 1) break;
        if (tid == 0) {
            int r = __hip_atomic_fetch_add(sliceCnt, 1, __ATOMIC_RELAXED,
                                           __HIP_MEMORY_SCOPE_AGENT);
            if (r == 64 * (t + 1) - 1)
                __hip_atomic_store(mySlice, t + 1, __ATOMIC_RELAXED,
                                   __HIP_MEMORY_SCOPE_AGENT);
        }
    }
}

// out[b][col] = sum over 512 block partials + bias.
__global__ __launch_bounds__(256) void finalize_persist(
    const float* __restrict__ pout, const float* __restrict__ b_ans,
    float* __restrict__ out)
{
    __shared__ float r[256];
    int col = blockIdx.x;
    int tid = threadIdx.x;
    int b = tid & 63, q = tid >> 6;
    float s = 0.f;
    for (int i = q; i < NBLK; i += 4)
        s += pout[((size_t)col * NBLK + i) * 64 + b];
    r[tid] = s;
    __syncthreads();
    if (tid < 64)
        out[tid * NOUT + col] = r[tid] + r[64 + tid] + r[128 + tid] + r[192 + tid]
                              + b_ans[0];
}

// ===================== per-step fallback (round-3 proven) =====================
#define F_HEADOFF 4096
__global__ __launch_bounds__(1024, 4) void lstm_step_fb(
    const float* __restrict__ xT, const float* __restrict__ hT_in,
    float* __restrict__ hT_out, float* __restrict__ cT,
    const float* __restrict__ w_ih, const float* __restrict__ w_hh,
    const float* __restrict__ b_ih, const float* __restrict__ b_hh,
    const float* __restrict__ w_ans, float* __restrict__ pout, int t)
{
    __shared__ float lds[F_HEADOFF + 256];
    const int tid = threadIdx.x;
    const int bid = blockIdx.x;
    const int b   = tid & 63;
    const int ws  = __builtin_amdgcn_readfirstlane(tid >> 6);
    const int uu  = ws & 3;
    const int ksl = ws >> 2;
    const int u   = bid * 4 + uu;

    const float* wr_i[4];
    const float* wr_h[4];
    #pragma unroll
    for (int j = 0; j < 4; ++j) {
        wr_i[j] = w_ih + (size_t)(j * HID + u) * EMBED;
        wr_h[j] = w_hh + (size_t)(j * HID + u) * HID;
    }
    float acc[4];
    acc[0] = acc[1] = acc[2] = acc[3] = 0.f;
    {
        const float* xt = xT + (size_t)t * EMBED * 64;
        const int k0 = ksl * 128;
        #pragma unroll 4
        for (int g = 0; g < 32; ++g) {
            const int k = k0 + g * 4;
            float4 wv0 = *(const float4*)(wr_i[0] + k);
            float4 wv1 = *(const float4*)(wr_i[1] + k);
            float4 wv2 = *(const float4*)(wr_i[2] + k);
            float4 wv3 = *(const float4*)(wr_i[3] + k);
            float x0 = xt[(k + 0) * 64 + b];
            float x1 = xt[(k + 1) * 64 + b];
            float x2 = xt[(k + 2) * 64 + b];
            float x3 = xt[(k + 3) * 64 + b];
            acc[0] = fmaf(wv0.x, x0, acc[0]); acc[0] = fmaf(wv0.y, x1, acc[0]);
            acc[0] = fmaf(wv0.z, x2, acc[0]); acc[0] = fmaf(wv0.w, x3, acc[0]);
            acc[1] = fmaf(wv1.x, x0, acc[1]); acc[1] = fmaf(wv1.y, x1, acc[1]);
            acc[1] = fmaf(wv1.z, x2, acc[1]); acc[1] = fmaf(wv1.w, x3, acc[1]);
            acc[2] = fmaf(wv2.x, x0, acc[2]); acc[2] = fmaf(wv2.y, x1, acc[2]);
            acc[2] = fmaf(wv2.z, x2, acc[2]); acc[2] = fmaf(wv2.w, x3, acc[2]);
            acc[3] = fmaf(wv3.x, x0, acc[3]); acc[3] = fmaf(wv3.y, x1, acc[3]);
            acc[3] = fmaf(wv3.z, x2, acc[3]); acc[3] = fmaf(wv3.w, x3, acc[3]);
        }
    }
    {
        const int k0 = ksl * 256;
        #pragma unroll 4
        for (int g = 0; g < 64; ++g) {
            const int k = k0 + g * 4;
            float4 wv0 = *(const float4*)(wr_h[0] + k);
            float4 wv1 = *(const float4*)(wr_h[1] + k);
            float4 wv2 = *(const float4*)(wr_h[2] + k);
            float4 wv3 = *(const float4*)(wr_h[3] + k);
            float x0 = hT_in[(k + 0) * 64 + b];
            float x1 = hT_in[(k + 1) * 64 + b];
            float x2 = hT_in[(k + 2) * 64 + b];
            float x3 = hT_in[(k + 3) * 64 + b];
            acc[0] = fmaf(wv0.x, x0, acc[0]); acc[0] = fmaf(wv0.y, x1, acc[0]);
            acc[0] = fmaf(wv0.z, x2, acc[0]); acc[0] = fmaf(wv0.w, x3, acc[0]);
            acc[1] = fmaf(wv1.x, x0, acc[1]); acc[1] = fmaf(wv1.y, x1, acc[1]);
            acc[1] = fmaf(wv1.z, x2, acc[1]); acc[1] = fmaf(wv1.w, x3, acc[1]);
            acc[2] = fmaf(wv2.x, x0, acc[2]); acc[2] = fmaf(wv2.y, x1, acc[2]);
            acc[2] = fmaf(wv2.z, x2, acc[2]); acc[2] = fmaf(wv2.w, x3, acc[2]);
            acc[3] = fmaf(wv3.x, x0, acc[3]); acc[3] = fmaf(wv3.y, x1, acc[3]);
            acc[3] = fmaf(wv3.z, x2, acc[3]); acc[3] = fmaf(wv3.w, x3, acc[3]);
        }
    }
    #pragma unroll
    for (int j = 0; j < 4; ++j)
        lds[((ksl * 4 + uu) * 4 + j) * 64 + b] = acc[j];
    __syncthreads();
    if (tid < 256) {
        int b2  = tid & 63;
        int uu2 = tid >> 6;
        int u2  = bid * 4 + uu2;
        float s[4];
        #pragma unroll
        for (int j = 0; j < 4; ++j) {
            s[j] = lds[((0 * 4 + uu2) * 4 + j) * 64 + b2]
                 + lds[((1 * 4 + uu2) * 4 + j) * 64 + b2]
                 + lds[((2 * 4 + uu2) * 4 + j) * 64 + b2]
                 + lds[((3 * 4 + uu2) * 4 + j) * 64 + b2];
            int rj = j * HID + u2;
            s[j] += b_ih[rj] + b_hh[rj];
        }
        float ig = sigmoidf_(s[0]);
        float fg = sigmoidf_(s[1]);
        float gg = tanhf(s[2]);
        float og = sigmoidf_(s[3]);
        float cn = fg * cT[u2 * 64 + b2] + ig * gg;
        float hn = og * tanhf(cn);
        cT[u2 * 64 + b2]     = cn;
        hT_out[u2 * 64 + b2] = hn;
        lds[F_HEADOFF + uu2 * 64 + b2] = hn * w_ans[u2];
    }
    __syncthreads();
    if (t >= OUT0 && tid < 64) {
        float sum = lds[F_HEADOFF + tid]       + lds[F_HEADOFF + 64 + tid]
                  + lds[F_HEADOFF + 128 + tid] + lds[F_HEADOFF + 192 + tid];
        pout[((size_t)((t - OUT0) * 64 + tid)) * 256 + bid] = sum;
    }
}

__global__ __launch_bounds__(64) void finalize_fb(
    const float* __restrict__ pout, const float* __restrict__ b_ans,
    float* __restrict__ out)
{
    int blk  = blockIdx.x;
    int col  = blk >> 6;
    int bb   = blk & 63;
    int lane = threadIdx.x;
    const float* p = pout + (size_t)(col * 64 + bb) * 256;
    float s = p[lane] + p[lane + 64] + p[lane + 128] + p[lane + 192];
    #pragma unroll
    for (int off = 32; off > 0; off >>= 1) s += __shfl_down(s, off);
    if (lane == 0) out[bb * NOUT + col] = s + b_ans[0];
}

extern "C" void kernel_launch(void* const* d_in, const int* in_sizes, int n_in,
                              void* d_out, int out_size, void* d_ws, size_t ws_size,
                              hipStream_t stream)
{
    const int*   prob  = (const int*)  d_in[0];
    const float* embed = (const float*)d_in[2];
    const float* w_ih  = (const float*)d_in[3];
    const float* w_hh  = (const float*)d_in[4];
    const float* b_ih  = (const float*)d_in[5];
    const float* b_hh  = (const float*)d_in[6];
    const float* w_ans = (const float*)d_in[7];
    const float* b_ans = (const float*)d_in[8];
    const float* h0    = (const float*)d_in[9];
    const float* c0    = (const float*)d_in[10];

    float* ws = (float*)d_ws;

    float* cT     = ws;                    // 65,536
    float* pout   = ws + 65536;            // 2,031,616
    float* xT     = ws + 2097152;          // 4,161,536
    float* h_hist = ws + 6258688;          // 128*65,536 = 8,388,608
    int*   bar    = (int*)(ws + 14647296); // 512 ints

    hipMemsetAsync(bar, 0, 2048, stream);
    init_state<<<256, 256, 0, stream>>>(h0, c0, h_hist, cT);
    embed_transpose<<<NSTEP, 256, 0, stream>>>(prob, embed, xT);

    void* args[] = {
        (void*)&xT, (void*)&h_hist, (void*)&cT,
        (void*)&w_ih, (void*)&w_hh, (void*)&b_ih, (void*)&b_hh,
        (void*)&w_ans, (void*)&pout, (void*)&bar
    };
    hipError_t err = hipLaunchCooperativeKernel((const void*)lstm_persist_hist,
                                                dim3(NBLK), dim3(NTHR),
                                                args, 0, stream);
    if (err == hipSuccess) {
        finalize_persist<<<NOUT, 256, 0, stream>>>(pout, b_ans, (float*)d_out);
    } else {
        for (int t = 0; t < NSTEP; ++t) {
            float* hin  = h_hist + (size_t)(t & 1) * 65536;
            float* hout = h_hist + (size_t)((t + 1) & 1) * 65536;
            lstm_step_fb<<<256, 1024, 0, stream>>>(xT, hin, hout, cT, w_ih, w_hh,
                                                   b_ih, b_hh, w_ans, pout, t);
        }
        finalize_fb<<<NOUT * 64, 64, 0, stream>>>(pout, b_ans, (float*)d_out);
    }
}